// Round 8
// baseline (152.146 us; speedup 1.0000x reference)
//
#include <hip/hip_runtime.h>
#include <hip/hip_bf16.h>

#define N 8192
#define D_IN 512
#define D_OUT 64
#define ALPHA 0.2f
#define BM 16
#define NSPLIT 4
#define KSEG (N / NSPLIT)       // 2048 cols per split
#define NSH (KSEG / 128)        // 16 steps/block; each wave does 32 cols/step

typedef __attribute__((ext_vector_type(4))) float f32x4;
typedef __attribute__((ext_vector_type(8))) short bf16x8;

static __device__ __forceinline__ unsigned pk_bf16(float lo, float hi) {
    unsigned ulo = __bfloat16_as_ushort(__float2bfloat16(lo));
    unsigned uhi = __bfloat16_as_ushort(__float2bfloat16(hi));
    return (uhi << 16) | ulo;
}

// Kernel 1: h = input @ W; emit h^T as pre-swizzled MFMA B-fragments.
// Fragment (kw = j>>5, dw = d>>4), 1 KB each, kw-major then dw:
// element offset = ((kw*4+dw)*64 + (kb*16|dd))*8 + e, where j = kw*32+kb*8+e, d = dw*16+dd.
// Also s1 = h@a1, s2 = h@a2 (fp32).
__global__ __launch_bounds__(256) void gat_h_kernel(
    const float* __restrict__ input, const float* __restrict__ W,
    const float* __restrict__ a, unsigned short* __restrict__ hpk,
    float* __restrict__ s1, float* __restrict__ s2)
{
    int wave = (blockIdx.x * 256 + threadIdx.x) >> 6;
    int lane = threadIdx.x & 63;
    int row0 = wave * 4;                      // 4 consecutive j (k-dim of PV matmul)
    const float* in0 = input + (size_t)row0 * D_IN;
    float a1 = a[lane], a2 = a[D_OUT + lane];
    float acc[4];
#pragma unroll
    for (int r = 0; r < 4; ++r) acc[r] = 0.f;
#pragma unroll 4
    for (int k = 0; k < D_IN; ++k) {
        float wk = W[k * D_OUT + lane];
#pragma unroll
        for (int r = 0; r < 4; ++r)
            acc[r] = fmaf(in0[(size_t)r * D_IN + k], wk, acc[r]);  // uniform-addr broadcast
    }
    // scatter into fragment layout (4 consecutive e-slots -> one uint2 store)
    {
        int kw = row0 >> 5, kb = (row0 >> 3) & 3, e0 = row0 & 7;   // e0 in {0,4}
        int dw = lane >> 4, dd = lane & 15;
        size_t off = ((size_t)((kw * 4 + dw) * 64) + kb * 16 + dd) * 8 + e0;
        uint2 hv;
        hv.x = pk_bf16(acc[0], acc[1]);
        hv.y = pk_bf16(acc[2], acc[3]);
        *(uint2*)(hpk + off) = hv;
    }
#pragma unroll
    for (int r = 0; r < 4; ++r) {
        float p1 = acc[r] * a1;
        float p2 = acc[r] * a2;
#pragma unroll
        for (int off = 32; off; off >>= 1) {
            p1 += __shfl_xor(p1, off, 64);
            p2 += __shfl_xor(p2, off, 64);
        }
        if (lane == 0) { s1[row0 + r] = p1; s2[row0 + r] = p2; }
    }
}

struct ASP { float4 a0, a1, s0, s1; };   // adj + s2, one 32-col step slice per lane-window
struct UBP { uint4 b0, b1, b2, b3; };    // 4 d-window B-fragments for one 32-k window

static __device__ __forceinline__ void issue_as(ASP& p, const float* ab,
                                                const float* sb, int ps) {
    const float* a = ab + ps * 128;
    const float* s = sb + ps * 128;
    p.a0 = *(const float4*)(a);
    p.a1 = *(const float4*)(a + 4);
    p.s0 = *(const float4*)(s);          // shared by 16 lanes -> L1
    p.s1 = *(const float4*)(s + 4);
}
static __device__ __forceinline__ void issue_ub(UBP& p, const unsigned short* hb,
                                                int ps) {
    const unsigned short* f = hb + ((size_t)ps << 13);   // 4 kw per step = 8192 elem
    p.b0 = *(const uint4*)(f);
    p.b1 = *(const uint4*)(f + 512);
    p.b2 = *(const uint4*)(f + 1024);
    p.b3 = *(const uint4*)(f + 1536);
}

// Kernel 2: dense masked-softmax @ h via MFMA — BARRIER-FREE main loop.
// Block = 16 rows x 64 d x KSEG cols. Wave ws owns the 32-col k-slice
// [step*128 + ws*32, +32): lane (kb=lane>>4, i=lane&15) computes
// w[8] = P[row i][kb*8+e] — natively the MFMA A-fragment. 4 MFMAs/step
// (d-windows, B straight from hpk/L2). acc = k-partial of full 16x64 C;
// one LDS combine per block at the end. No __syncthreads in the loop.
__global__ __launch_bounds__(256, 4) void gat_flash_kernel(
    const float* __restrict__ adj, const unsigned short* __restrict__ hpk,
    const float* __restrict__ s1, const float* __restrict__ s2,
    float* __restrict__ pacc, float* __restrict__ plsum)
{
    __shared__ float Cl[4][BM][D_OUT];   // 16 KB, used once at end
    __shared__ float lsl[4][BM];

    const int tid  = threadIdx.x;
    const int lane = tid & 63;
    const int ws   = tid >> 6;
    const int i    = lane & 15;          // adj row within tile (A-frag row)
    const int kb   = lane >> 4;          // k-subwindow within 32
    const int hf   = blockIdx.x >> 9;    // k-split 0..3
    const int rb   = blockIdx.x & 511;   // row-block
    const int rg   = rb * BM + i;

    const int col0 = hf * KSEG + ws * 32 + kb * 8;
    const float* adj_lane = adj + (size_t)rg * N + col0;
    const float* s2_lane  = s2 + col0;
    // kw for step p: hf*64 + p*4 + ws
    const unsigned short* hb_lane =
        hpk + (((size_t)(hf * 64 + ws)) << 11) + (lane << 3);

    float s1r  = s1[rg];
    float eref = s1r + s2[rg];                    // diagonal logit (adj[i][i]=1)
    eref = eref > 0.f ? eref : ALPHA * eref;      // leaky_relu
    float lsum = 0.f;
    f32x4 acc0 = {0,0,0,0}, acc1 = {0,0,0,0}, acc2 = {0,0,0,0}, acc3 = {0,0,0,0};

    auto step = [&](const ASP& p, const UBP& u) {
        const float* av0 = (const float*)&p.a0;
        const float* av1 = (const float*)&p.a1;
        const float* sv0 = (const float*)&p.s0;
        const float* sv1 = (const float*)&p.s1;
        float w[8];
#pragma unroll
        for (int z = 0; z < 4; ++z) {
            float e0 = s1r + sv0[z]; e0 = e0 > 0.f ? e0 : ALPHA * e0;   // leaky_relu
            float e1 = s1r + sv1[z]; e1 = e1 > 0.f ? e1 : ALPHA * e1;
            float w0 = __expf(e0 - eref);
            float w1 = __expf(e1 - eref);
            w[z]     = av0[z] > 0.f ? w0 : 0.f;
            w[z + 4] = av1[z] > 0.f ? w1 : 0.f;
        }
#pragma unroll
        for (int z = 0; z < 8; ++z) lsum += w[z];
        uint4 pk;
        pk.x = pk_bf16(w[0], w[1]); pk.y = pk_bf16(w[2], w[3]);
        pk.z = pk_bf16(w[4], w[5]); pk.w = pk_bf16(w[6], w[7]);
        bf16x8 A = __builtin_bit_cast(bf16x8, pk);
        acc0 = __builtin_amdgcn_mfma_f32_16x16x32_bf16(A, __builtin_bit_cast(bf16x8, u.b0), acc0, 0, 0, 0);
        acc1 = __builtin_amdgcn_mfma_f32_16x16x32_bf16(A, __builtin_bit_cast(bf16x8, u.b1), acc1, 0, 0, 0);
        acc2 = __builtin_amdgcn_mfma_f32_16x16x32_bf16(A, __builtin_bit_cast(bf16x8, u.b2), acc2, 0, 0, 0);
        acc3 = __builtin_amdgcn_mfma_f32_16x16x32_bf16(A, __builtin_bit_cast(bf16x8, u.b3), acc3, 0, 0, 0);
    };

    ASP A0, A1; UBP U0, U1;
    issue_as(A0, adj_lane, s2_lane, 0); issue_ub(U0, hb_lane, 0);
    issue_as(A1, adj_lane, s2_lane, 1); issue_ub(U1, hb_lane, 1);
#pragma unroll 2
    for (int p = 0; p < NSH; p += 2) {
        step(A0, U0);
        if (p + 2 < NSH) { issue_as(A0, adj_lane, s2_lane, p + 2); issue_ub(U0, hb_lane, p + 2); }
        step(A1, U1);
        if (p + 3 < NSH) { issue_as(A1, adj_lane, s2_lane, p + 3); issue_ub(U1, hb_lane, p + 3); }
    }

    // lsum: lanes i, i+16, i+32, i+48 hold row-i k-slices of this wave
    lsum += __shfl_xor(lsum, 16, 64);
    lsum += __shfl_xor(lsum, 32, 64);
    if (lane < 16) lsl[ws][lane] = lsum;

    // C k-partials: row = kb*4+reg, col = dw*16+i  (C/D frag layout)
    const f32x4 av[4] = {acc0, acc1, acc2, acc3};
#pragma unroll
    for (int dw = 0; dw < 4; ++dw)
#pragma unroll
        for (int reg = 0; reg < 4; ++reg)
            Cl[ws][kb * 4 + reg][dw * 16 + i] = av[dw][reg];
    __syncthreads();

#pragma unroll
    for (int o = tid; o < BM * D_OUT; o += 256) {
        int row = o >> 6, d = o & 63;
        float v = (Cl[0][row][d] + Cl[1][row][d]) + (Cl[2][row][d] + Cl[3][row][d]);
        pacc[((size_t)hf * N + rb * BM + row) * 64 + d] = v;
    }
    if (tid < BM)
        plsum[hf * N + rb * BM + tid] =
            (lsl[0][tid] + lsl[1][tid]) + (lsl[2][tid] + lsl[3][tid]);
}

// Kernel 3: combine the 4 k-splits, normalize, elu.
__global__ __launch_bounds__(256) void gat_reduce_kernel(
    const float* __restrict__ pacc, const float* __restrict__ plsum,
    float* __restrict__ out)
{
    int idx = blockIdx.x * 256 + threadIdx.x;    // over N*64
    int row = idx >> 6;
    float aa = 0.f, l = 0.f;
#pragma unroll
    for (int hf = 0; hf < NSPLIT; ++hf) {
        aa += pacc[(size_t)hf * N * 64 + idx];
        l  += plsum[hf * N + row];
    }
    float o = aa / l;
    out[idx] = o > 0.f ? o : expm1f(o);          // elu
}

extern "C" void kernel_launch(void* const* d_in, const int* in_sizes, int n_in,
                              void* d_out, int out_size, void* d_ws, size_t ws_size,
                              hipStream_t stream) {
    const float* input = (const float*)d_in[0];   // (8192, 512) f32
    const float* adj   = (const float*)d_in[1];   // (8192, 8192) f32
    const float* W     = (const float*)d_in[2];   // (512, 64) f32
    const float* a     = (const float*)d_in[3];   // (128, 1) f32
    float* out = (float*)d_out;                   // (8192, 64) f32

    unsigned short* hpk = (unsigned short*)d_ws;          // 1 MB fragment buffer
    float* s1    = (float*)(hpk + (size_t)N * D_OUT);     // N f32
    float* s2    = s1 + N;                                // N f32
    float* pacc  = s2 + N;                                // NSPLIT*N*64 f32 = 8 MB
    float* plsum = pacc + (size_t)NSPLIT * N * 64;        // NSPLIT*N f32

    gat_h_kernel<<<512, 256, 0, stream>>>(input, W, a, hpk, s1, s2);
    gat_flash_kernel<<<512 * NSPLIT, 256, 0, stream>>>(adj, hpk, s1, s2, pacc, plsum);
    gat_reduce_kernel<<<N * 64 / 256, 256, 0, stream>>>(pacc, plsum, out);
}

// Round 9
// 124.080 us; speedup vs baseline: 1.2262x; 1.2262x over previous
//
#include <hip/hip_runtime.h>
#include <hip/hip_bf16.h>

#define N 8192
#define D_IN 512
#define D_OUT 64
#define ALPHA 0.2f
#define BM 16
#define NSPLIT 4
#define KSEG (N / NSPLIT)       // 2048 cols per split
#define NSH (KSEG / 128)        // 16 steps/block; each wave does 32 cols/step

typedef __attribute__((ext_vector_type(4))) float f32x4;
typedef __attribute__((ext_vector_type(8))) short bf16x8;

static __device__ __forceinline__ unsigned pk_bf16(float lo, float hi) {
    unsigned ulo = __bfloat16_as_ushort(__float2bfloat16(lo));
    unsigned uhi = __bfloat16_as_ushort(__float2bfloat16(hi));
    return (uhi << 16) | ulo;
}

// Kernel 1 (fused): blocks [0,512): h = input @ W -> pre-swizzled MFMA B-frags
// (hpk) + s1 = h@a1, s2 = h@a2. Blocks [512, 2560): adj -> 1-bit/elem mask
// (byte j-order: msk[f>>3] bit z = adj[f+z] > 0), pure streaming, fill-like.
__global__ __launch_bounds__(256) void gat_prep_kernel(
    const float* __restrict__ input, const float* __restrict__ adj,
    const float* __restrict__ W, const float* __restrict__ a,
    unsigned short* __restrict__ hpk, float* __restrict__ s1,
    float* __restrict__ s2, unsigned char* __restrict__ msk)
{
    if (blockIdx.x < 512) {
        // ---- h / s1 / s2 / hpk (validated R7/R8 code) ----
        int wave = (blockIdx.x * 256 + threadIdx.x) >> 6;
        int lane = threadIdx.x & 63;
        int row0 = wave * 4;
        const float* in0 = input + (size_t)row0 * D_IN;
        float a1 = a[lane], a2 = a[D_OUT + lane];
        float acc[4];
#pragma unroll
        for (int r = 0; r < 4; ++r) acc[r] = 0.f;
#pragma unroll 4
        for (int k = 0; k < D_IN; ++k) {
            float wk = W[k * D_OUT + lane];
#pragma unroll
            for (int r = 0; r < 4; ++r)
                acc[r] = fmaf(in0[(size_t)r * D_IN + k], wk, acc[r]);
        }
        {
            int kw = row0 >> 5, kb = (row0 >> 3) & 3, e0 = row0 & 7;
            int dw = lane >> 4, dd = lane & 15;
            size_t off = ((size_t)((kw * 4 + dw) * 64) + kb * 16 + dd) * 8 + e0;
            uint2 hv;
            hv.x = pk_bf16(acc[0], acc[1]);
            hv.y = pk_bf16(acc[2], acc[3]);
            *(uint2*)(hpk + off) = hv;
        }
#pragma unroll
        for (int r = 0; r < 4; ++r) {
            float p1 = acc[r] * a1;
            float p2 = acc[r] * a2;
#pragma unroll
            for (int off = 32; off; off >>= 1) {
                p1 += __shfl_xor(p1, off, 64);
                p2 += __shfl_xor(p2, off, 64);
            }
            if (lane == 0) { s1[row0 + r] = p1; s2[row0 + r] = p2; }
        }
    } else {
        // ---- adj -> bitmask stream (no sync, no cross-lane, fill-like) ----
        size_t wave = (((size_t)blockIdx.x - 512) * 256 + threadIdx.x) >> 6;
        int lane = threadIdx.x & 63;
#pragma unroll 4
        for (int it = 0; it < 16; ++it) {
            size_t fo = (wave * 16 + it) * 512 + (size_t)lane * 8;
            float4 v0 = *(const float4*)(adj + fo);
            float4 v1 = *(const float4*)(adj + fo + 4);
            unsigned b =  (unsigned)(v0.x > 0.f)
                       | ((unsigned)(v0.y > 0.f) << 1)
                       | ((unsigned)(v0.z > 0.f) << 2)
                       | ((unsigned)(v0.w > 0.f) << 3)
                       | ((unsigned)(v1.x > 0.f) << 4)
                       | ((unsigned)(v1.y > 0.f) << 5)
                       | ((unsigned)(v1.z > 0.f) << 6)
                       | ((unsigned)(v1.w > 0.f) << 7);
            msk[fo >> 3] = (unsigned char)b;
        }
    }
}

struct MSP { unsigned m; float4 sA, sB; };   // mask byte + s2 pair for one 32-col slice
struct UBP { uint4 b0, b1, b2, b3; };        // 4 d-window B-fragments for one 32-k window

static __device__ __forceinline__ void issue_ms(MSP& p, const unsigned char* mb,
                                                const float* sb, int ps) {
    p.m  = mb[ps * 16];                      // (128 cols)/8 per step
    p.sA = *(const float4*)(sb + ps * 128);
    p.sB = *(const float4*)(sb + ps * 128 + 4);
}
static __device__ __forceinline__ void issue_ub(UBP& p, const unsigned short* hb,
                                                int ps) {
    const unsigned short* f = hb + ((size_t)ps << 13);
    p.b0 = *(const uint4*)(f);
    p.b1 = *(const uint4*)(f + 512);
    p.b2 = *(const uint4*)(f + 1024);
    p.b3 = *(const uint4*)(f + 1536);
}

// Kernel 2: masked-softmax @ h via MFMA — barrier-free, all inputs L2-resident.
// Block = 16 rows x 64 d x KSEG cols, split-K x4. Wave ws owns 32-col slices;
// lane (kb=lane>>4, i=lane&15) computes w[8] = P[row i][kb*8+e] natively as the
// MFMA A-fragment (validated R8). B-frags straight from hpk (L2). Mask byte
// replaces the 32-B adj read. One LDS combine at block end.
__global__ __launch_bounds__(256, 4) void gat_flash_kernel(
    const unsigned char* __restrict__ msk, const unsigned short* __restrict__ hpk,
    const float* __restrict__ s1, const float* __restrict__ s2,
    float* __restrict__ pacc, float* __restrict__ plsum)
{
    __shared__ float Cl[4][BM][D_OUT];   // 16 KB, used once at end
    __shared__ float lsl[4][BM];

    const int tid  = threadIdx.x;
    const int lane = tid & 63;
    const int ws   = tid >> 6;
    const int i    = lane & 15;          // adj row within tile (A-frag row)
    const int kb   = lane >> 4;          // k-subwindow within 32
    const int hf   = blockIdx.x >> 9;    // k-split 0..3
    const int rb   = blockIdx.x & 511;   // row-block
    const int rg   = rb * BM + i;

    const int col0 = hf * KSEG + ws * 32 + kb * 8;
    const unsigned char* mb_lane = msk + ((size_t)rg << 10) + (col0 >> 3);
    const float* s2_lane = s2 + col0;
    const unsigned short* hb_lane =
        hpk + (((size_t)(hf * 64 + ws)) << 11) + (lane << 3);

    float s1r  = s1[rg];
    float eref = s1r + s2[rg];                    // diagonal logit (adj[i][i]=1)
    eref = eref > 0.f ? eref : ALPHA * eref;      // leaky_relu
    float lsum = 0.f;
    f32x4 acc0 = {0,0,0,0}, acc1 = {0,0,0,0}, acc2 = {0,0,0,0}, acc3 = {0,0,0,0};

    auto step = [&](const MSP& p, const UBP& u) {
        const float* sv0 = (const float*)&p.sA;
        const float* sv1 = (const float*)&p.sB;
        float w[8];
#pragma unroll
        for (int z = 0; z < 4; ++z) {
            float e0 = s1r + sv0[z]; e0 = e0 > 0.f ? e0 : ALPHA * e0;   // leaky_relu
            float e1 = s1r + sv1[z]; e1 = e1 > 0.f ? e1 : ALPHA * e1;
            float w0 = __expf(e0 - eref);
            float w1 = __expf(e1 - eref);
            w[z]     = ((p.m >> z) & 1u)       ? w0 : 0.f;
            w[z + 4] = ((p.m >> (z + 4)) & 1u) ? w1 : 0.f;
        }
#pragma unroll
        for (int z = 0; z < 8; ++z) lsum += w[z];
        uint4 pk;
        pk.x = pk_bf16(w[0], w[1]); pk.y = pk_bf16(w[2], w[3]);
        pk.z = pk_bf16(w[4], w[5]); pk.w = pk_bf16(w[6], w[7]);
        bf16x8 A = __builtin_bit_cast(bf16x8, pk);
        acc0 = __builtin_amdgcn_mfma_f32_16x16x32_bf16(A, __builtin_bit_cast(bf16x8, u.b0), acc0, 0, 0, 0);
        acc1 = __builtin_amdgcn_mfma_f32_16x16x32_bf16(A, __builtin_bit_cast(bf16x8, u.b1), acc1, 0, 0, 0);
        acc2 = __builtin_amdgcn_mfma_f32_16x16x32_bf16(A, __builtin_bit_cast(bf16x8, u.b2), acc2, 0, 0, 0);
        acc3 = __builtin_amdgcn_mfma_f32_16x16x32_bf16(A, __builtin_bit_cast(bf16x8, u.b3), acc3, 0, 0, 0);
    };

    MSP M0, M1; UBP U0, U1;
    issue_ms(M0, mb_lane, s2_lane, 0); issue_ub(U0, hb_lane, 0);
    issue_ms(M1, mb_lane, s2_lane, 1); issue_ub(U1, hb_lane, 1);
#pragma unroll 2
    for (int p = 0; p < NSH; p += 2) {
        step(M0, U0);
        if (p + 2 < NSH) { issue_ms(M0, mb_lane, s2_lane, p + 2); issue_ub(U0, hb_lane, p + 2); }
        step(M1, U1);
        if (p + 3 < NSH) { issue_ms(M1, mb_lane, s2_lane, p + 3); issue_ub(U1, hb_lane, p + 3); }
    }

    // lsum: lanes i, i+16, i+32, i+48 hold row-i k-slices of this wave
    lsum += __shfl_xor(lsum, 16, 64);
    lsum += __shfl_xor(lsum, 32, 64);
    if (lane < 16) lsl[ws][lane] = lsum;

    // C k-partials: row = kb*4+reg, col = dw*16+i  (C/D frag layout)
    const f32x4 av[4] = {acc0, acc1, acc2, acc3};
#pragma unroll
    for (int dw = 0; dw < 4; ++dw)
#pragma unroll
        for (int reg = 0; reg < 4; ++reg)
            Cl[ws][kb * 4 + reg][dw * 16 + i] = av[dw][reg];
    __syncthreads();

#pragma unroll
    for (int o = tid; o < BM * D_OUT; o += 256) {
        int row = o >> 6, d = o & 63;
        float v = (Cl[0][row][d] + Cl[1][row][d]) + (Cl[2][row][d] + Cl[3][row][d]);
        pacc[((size_t)hf * N + rb * BM + row) * 64 + d] = v;
    }
    if (tid < BM)
        plsum[hf * N + rb * BM + tid] =
            (lsl[0][tid] + lsl[1][tid]) + (lsl[2][tid] + lsl[3][tid]);
}

// Kernel 3: combine the 4 k-splits, normalize, elu.
__global__ __launch_bounds__(256) void gat_reduce_kernel(
    const float* __restrict__ pacc, const float* __restrict__ plsum,
    float* __restrict__ out)
{
    int idx = blockIdx.x * 256 + threadIdx.x;    // over N*64
    int row = idx >> 6;
    float aa = 0.f, l = 0.f;
#pragma unroll
    for (int hf = 0; hf < NSPLIT; ++hf) {
        aa += pacc[(size_t)hf * N * 64 + idx];
        l  += plsum[hf * N + row];
    }
    float o = aa / l;
    out[idx] = o > 0.f ? o : expm1f(o);          // elu
}

extern "C" void kernel_launch(void* const* d_in, const int* in_sizes, int n_in,
                              void* d_out, int out_size, void* d_ws, size_t ws_size,
                              hipStream_t stream) {
    const float* input = (const float*)d_in[0];   // (8192, 512) f32
    const float* adj   = (const float*)d_in[1];   // (8192, 8192) f32
    const float* W     = (const float*)d_in[2];   // (512, 64) f32
    const float* a     = (const float*)d_in[3];   // (128, 1) f32
    float* out = (float*)d_out;                   // (8192, 64) f32

    unsigned short* hpk = (unsigned short*)d_ws;          // 1 MB fragment buffer
    float* s1    = (float*)(hpk + (size_t)N * D_OUT);     // N f32
    float* s2    = s1 + N;                                // N f32
    float* pacc  = s2 + N;                                // NSPLIT*N*64 f32 = 8 MB
    float* plsum = pacc + (size_t)NSPLIT * N * 64;        // NSPLIT*N f32
    unsigned char* msk = (unsigned char*)(plsum + NSPLIT * N);  // N*N/8 = 8 MB

    gat_prep_kernel<<<2560, 256, 0, stream>>>(input, adj, W, a, hpk, s1, s2, msk);
    gat_flash_kernel<<<512 * NSPLIT, 256, 0, stream>>>(msk, hpk, s1, s2, pacc, plsum);
    gat_reduce_kernel<<<N * 64 / 256, 256, 0, stream>>>(pacc, plsum, out);
}